// Round 3
// baseline (788.384 us; speedup 1.0000x reference)
//
#include <hip/hip_runtime.h>
#include <hip/hip_bf16.h>
#include <math.h>

// Problem constants
#define BD 8          // batch
#define SN 2048       // sequence length N
#define DM 1024       // d_model
#define NH 16         // heads
#define HD 64         // head dim
#define NS 11         // scales

typedef __attribute__((ext_vector_type(8))) short short8;
typedef __attribute__((ext_vector_type(4))) float floatx4;

// async global->LDS, 16B per lane; LDS dest = wave-uniform base + lane*16
__device__ __forceinline__ void async_load16(const void* g, void* lds) {
    __builtin_amdgcn_global_load_lds(
        (const __attribute__((address_space(1))) void*)g,
        (__attribute__((address_space(3))) void*)lds,
        16, 0, 0);
}

// ---------------------------------------------------------------------------
// fp32 -> bf16 convert (vectorized by 4)
// ---------------------------------------------------------------------------
__global__ __launch_bounds__(256) void f2bf_kernel(const float* __restrict__ src,
                                                   __hip_bfloat16* __restrict__ dst,
                                                   int n4) {
    int i = blockIdx.x * 256 + threadIdx.x;
    if (i < n4) {
        const float4 v = reinterpret_cast<const float4*>(src)[i];
        union { __hip_bfloat16 h[4]; uint2 u; } cv;
        cv.h[0] = __float2bfloat16(v.x);
        cv.h[1] = __float2bfloat16(v.y);
        cv.h[2] = __float2bfloat16(v.z);
        cv.h[3] = __float2bfloat16(v.w);
        reinterpret_cast<uint2*>(dst)[i] = cv.u;
    }
}

// ---------------------------------------------------------------------------
// tiny softmaxes
// ---------------------------------------------------------------------------
__global__ void prep_kernel(const float* __restrict__ scale_gain,
                            const float* __restrict__ field_coupling,
                            float* __restrict__ gains,
                            float* __restrict__ cw) {
    int t = threadIdx.x;
    if (t < NH) {
        float m = -1e30f;
        for (int j = 0; j < NS; ++j) m = fmaxf(m, scale_gain[j * NH + t]);
        float e[NS]; float s = 0.f;
        for (int j = 0; j < NS; ++j) { e[j] = expf(scale_gain[j * NH + t] - m); s += e[j]; }
        float inv = 1.f / s;
        for (int j = 0; j < NS; ++j) gains[j * NH + t] = e[j] * inv;
    } else if (t < 2 * NH) {
        int r = t - NH;
        float m = -1e30f;
        for (int j = 0; j < NH; ++j) m = fmaxf(m, field_coupling[r * NH + j]);
        float e[NH]; float s = 0.f;
        for (int j = 0; j < NH; ++j) { e[j] = expf(field_coupling[r * NH + j] - m); s += e[j]; }
        float inv = 1.f / s;
        for (int j = 0; j < NH; ++j) cw[r * NH + j] = e[j] * inv;
    }
}

// ---------------------------------------------------------------------------
// m97-class bf16 MFMA GEMM: C[M,Nn] = A[M,K] @ Bw[Nn,K]^T + bias
// 128x128 tile, BK=64, 256 thr = 4 waves (2x2), each wave 64x64 = 4x4 frags.
// Staging: global_load_lds 16B/lane with XOR-swizzled SOURCE addresses so that
//   LDS(row, chunk) holds global 16B-chunk (chunk ^ (row&7)); row = 128B = 8 chunks.
//   -> frag ds_read_b128 spreads across all 8 chunk positions (2-way/bank = free).
// mfma_f32_16x16x32_bf16 layouts (HW-verified, round-2 kernel passed):
//   A frag: A[m = lane&15][k = quad*8 + j]
//   B frag: Bw[n = lane&15][k = quad*8 + j]
//   C/D  : col = lane&15, row = quad*4 + reg
// ---------------------------------------------------------------------------
__global__ __launch_bounds__(256, 3) void gemm128_kernel(
    const __hip_bfloat16* __restrict__ A,
    const __hip_bfloat16* __restrict__ Bw,
    void* __restrict__ Cout,
    const float* __restrict__ bias,
    int M, int Nn, int K, int act, int bf16out) {
    __shared__ short As[128 * 64];   // 16 KB, row stride 128B, no padding (swizzled)
    __shared__ short Bs[128 * 64];

    const int tid = threadIdx.x;
    const int m0 = blockIdx.y * 128;
    const int n0 = blockIdx.x * 128;
    const int wv = tid >> 6;
    const int ln = tid & 63;

    // ---- staging pattern (per lane, invariant over K) ----
    const int srow = ln >> 3;              // row within 8-row group
    const int scc  = (ln & 7) ^ srow;      // swizzled source chunk
    // wave wv stages rows [wv*32, wv*32+32) of both tiles, 4 insts x 8 rows
    size_t goffA[4], goffB[4];
    #pragma unroll
    for (int i = 0; i < 4; ++i) {
        const int row = wv * 32 + i * 8 + srow;
        goffA[i] = (size_t)(m0 + row) * K + scc * 8;
        goffB[i] = (size_t)(n0 + row) * K + scc * 8;
    }

    // ---- compute pattern ----
    const int lrow = ln & 15, quad = ln >> 4;
    const int wm = (wv >> 1) * 64;
    const int wn = (wv & 1) * 64;
    int aaddr[4], baddr[4];                 // byte addrs, k-half 0 (h1 = ^64)
    #pragma unroll
    for (int t = 0; t < 4; ++t) {
        const int sw = (quad ^ (lrow & 7)) * 16;
        aaddr[t] = (wm + t * 16 + lrow) * 128 + sw;
        baddr[t] = (wn + t * 16 + lrow) * 128 + sw;
    }

    floatx4 acc[4][4];
    #pragma unroll
    for (int a = 0; a < 4; ++a)
        #pragma unroll
        for (int b = 0; b < 4; ++b) acc[a][b] = (floatx4){0.f, 0.f, 0.f, 0.f};

    for (int kt = 0; kt < K; kt += 64) {
        #pragma unroll
        for (int i = 0; i < 4; ++i) {
            async_load16(A + goffA[i] + kt, &As[(wv * 32 + i * 8) * 64]);
            async_load16(Bw + goffB[i] + kt, &Bs[(wv * 32 + i * 8) * 64]);
        }
        __syncthreads();
        #pragma unroll
        for (int h = 0; h < 2; ++h) {
            short8 a[4], b[4];
            #pragma unroll
            for (int t = 0; t < 4; ++t) {
                a[t] = *reinterpret_cast<const short8*>(
                           reinterpret_cast<const char*>(As) + (aaddr[t] ^ (h * 64)));
                b[t] = *reinterpret_cast<const short8*>(
                           reinterpret_cast<const char*>(Bs) + (baddr[t] ^ (h * 64)));
            }
            #pragma unroll
            for (int mt = 0; mt < 4; ++mt)
                #pragma unroll
                for (int nt = 0; nt < 4; ++nt)
                    acc[mt][nt] = __builtin_amdgcn_mfma_f32_16x16x32_bf16(
                        a[mt], b[nt], acc[mt][nt], 0, 0, 0);
        }
        __syncthreads();
    }

    #pragma unroll
    for (int mt = 0; mt < 4; ++mt) {
        #pragma unroll
        for (int nt = 0; nt < 4; ++nt) {
            const int col = n0 + wn + nt * 16 + lrow;
            const float bv = bias ? bias[col] : 0.f;
            #pragma unroll
            for (int i = 0; i < 4; ++i) {
                const int row = m0 + wm + mt * 16 + quad * 4 + i;
                float val = acc[mt][nt][i] + bv;
                if (act == 1) val = 1.f / (1.f + expf(-val));
                if (bf16out)
                    ((__hip_bfloat16*)Cout)[(size_t)row * Nn + col] = __float2bfloat16(val);
                else
                    ((float*)Cout)[(size_t)row * Nn + col] = val;
            }
        }
    }
}

// ---------------------------------------------------------------------------
// fieldize: field[b, h*64+d, n] = v[b,n,h,d] * ||k[b,n,h,:]||   (bf16 in/out)
// kv row r=b*N+n: cols [0,1024)=k, [1024,2048)=v
// ---------------------------------------------------------------------------
__global__ __launch_bounds__(256) void fieldize_kernel(const __hip_bfloat16* __restrict__ kv,
                                                       __hip_bfloat16* __restrict__ field) {
    const int b = blockIdx.z, h = blockIdx.y, n0 = blockIdx.x * 64;
    __shared__ float kt[64][65];
    __shared__ float vt[64][65];
    __shared__ float mag[64];
    const int t = threadIdx.x;
    #pragma unroll
    for (int i = 0; i < 16; ++i) {
        int idx = t + i * 256;
        int nl = idx >> 6, d = idx & 63;
        size_t rbase = (size_t)(b * SN + n0 + nl) * 2048;
        kt[nl][d] = __bfloat162float(kv[rbase + h * 64 + d]);
        vt[nl][d] = __bfloat162float(kv[rbase + 1024 + h * 64 + d]);
    }
    __syncthreads();
    if (t < 64) {
        float s = 0.f;
        #pragma unroll
        for (int d = 0; d < 64; ++d) { float x = kt[t][d]; s += x * x; }
        mag[t] = sqrtf(s);
    }
    __syncthreads();
    #pragma unroll
    for (int i = 0; i < 16; ++i) {
        int idx = t + i * 256;
        int d = idx >> 6, nl = idx & 63;
        field[((size_t)b * DM + h * 64 + d) * SN + n0 + nl] =
            __float2bfloat16(vt[nl][d] * mag[nl]);
    }
}

// ---------------------------------------------------------------------------
// fused wavelet + head coupling, IN-PLACE on field.
// Block per (b,d): stages all 16 head-rows at this d (16 x 2048 bf16 = 64KB LDS),
// computes per-n the 16 wavelet outputs, mixes with coupling weights, writes the
// same 16 rows back. Safe in-place: block reads only its own (b,*,d,*) addresses
// into LDS before any write. gains/cw read as wave-uniform scalar loads.
// ---------------------------------------------------------------------------
__global__ __launch_bounds__(256) void wavecouple_kernel(
    const float* __restrict__ gains,   // [NS][NH]
    const float* __restrict__ cw,      // [NH][NH]
    __hip_bfloat16* __restrict__ field) {
    const int b = blockIdx.x >> 6;
    const int d = blockIdx.x & 63;
    __shared__ __hip_bfloat16 rows[NH][SN];   // 64 KB
    const int t = threadIdx.x;

    // stage 16 rows (4096 chunks of 16B)
    for (int i = t; i < NH * SN / 8; i += 256) {
        const int hi = i >> 8;            // 256 chunks per row
        const int ch = i & 255;
        *reinterpret_cast<uint4*>(&rows[hi][ch * 8]) =
            *reinterpret_cast<const uint4*>(
                &field[((size_t)b * DM + hi * 64 + d) * SN + ch * 8]);
    }
    __syncthreads();

    const float d0 = 0.4829629131445341f, d1 = 0.8365163037378079f,
                d2 = 0.2241438680420134f, d3 = -0.1294095225512604f;

    for (int n = t; n < SN; n += 256) {
        float wvv[NH];
        #pragma unroll
        for (int hi = 0; hi < NH; ++hi) {
            float acc = 0.f;
            const float x3 = __bfloat162float(rows[hi][n]);
            #pragma unroll
            for (int j = 0; j < NS; ++j) {
                const int dd = 1 << j;
                const float x2 = (n >= dd)     ? __bfloat162float(rows[hi][n - dd])     : 0.f;
                const float x1 = (n >= 2 * dd) ? __bfloat162float(rows[hi][n - 2 * dd]) : 0.f;
                const float x0 = (n >= 3 * dd) ? __bfloat162float(rows[hi][n - 3 * dd]) : 0.f;
                acc += gains[j * NH + hi] * (d0 * x0 + d1 * x1 + d2 * x2 + d3 * x3);
            }
            wvv[hi] = acc;
        }
        #pragma unroll
        for (int ho = 0; ho < NH; ++ho) {
            float s = 0.f;
            #pragma unroll
            for (int hi = 0; hi < NH; ++hi) s += cw[ho * NH + hi] * wvv[hi];
            field[((size_t)b * DM + ho * 64 + d) * SN + n] = __float2bfloat16(s);
        }
    }
}

// ---------------------------------------------------------------------------
// transpose + gate: Ag[b*N+n, c] = bf16( cpl[b,c,n] * gate[b*N+n, c] )
// ---------------------------------------------------------------------------
__global__ __launch_bounds__(256) void transgate_kernel(const __hip_bfloat16* __restrict__ cpl,
                                                        const __hip_bfloat16* __restrict__ gate,
                                                        __hip_bfloat16* __restrict__ Ag) {
    const int b = blockIdx.z;
    const int c0 = blockIdx.y * 64, n0 = blockIdx.x * 64;
    __shared__ float tile[64][65];
    const int t = threadIdx.x;
    #pragma unroll
    for (int i = 0; i < 16; ++i) {
        int idx = t + i * 256;
        int ci = idx >> 6, nj = idx & 63;
        tile[ci][nj] = __bfloat162float(cpl[((size_t)b * DM + c0 + ci) * SN + n0 + nj]);
    }
    __syncthreads();
    #pragma unroll
    for (int i = 0; i < 16; ++i) {
        int idx = t + i * 256;
        int nj = idx >> 6, ci = idx & 63;
        size_t off = ((size_t)(b * SN + n0 + nj)) * DM + c0 + ci;
        Ag[off] = __float2bfloat16(tile[ci][nj] * __bfloat162float(gate[off]));
    }
}

// ---------------------------------------------------------------------------
// launch
// ws footprint ~109 MB; kv staged in d_out (exactly 67,108,864 B)
// ---------------------------------------------------------------------------
extern "C" void kernel_launch(void* const* d_in, const int* in_sizes, int n_in,
                              void* d_out, int out_size, void* d_ws, size_t ws_size,
                              hipStream_t stream) {
    const float* x     = (const float*)d_in[0];
    const float* qkv_w = (const float*)d_in[1];
    const float* qkv_b = (const float*)d_in[2];
    const float* out_w = (const float*)d_in[3];
    const float* out_b = (const float*)d_in[4];
    const float* gate_w = (const float*)d_in[5];
    const float* gate_b = (const float*)d_in[6];
    const float* scale_gain = (const float*)d_in[7];
    const float* field_coupling = (const float*)d_in[8];

    char* ws = (char*)d_ws;
    const int M = BD * SN;          // 16384

    // ws layout (bytes)
    __hip_bfloat16* x_bf   = (__hip_bfloat16*)(ws);               // 33,554,432
    __hip_bfloat16* wkv_bf = (__hip_bfloat16*)(ws + 33554432);    //  4,194,304
    __hip_bfloat16* wg_bf  = (__hip_bfloat16*)(ws + 37748736);    //  2,097,152
    __hip_bfloat16* wo_bf  = (__hip_bfloat16*)(ws + 39845888);    //  2,097,152
    float* gains           = (float*)(ws + 41943040);             //        704
    float* cwbuf           = (float*)(ws + 41944064);             //      1,024
    __hip_bfloat16* gate_bf  = (__hip_bfloat16*)(ws + 41945088);  // 33,554,432
    __hip_bfloat16* field_bf = (__hip_bfloat16*)(ws + 75499520);  // 33,554,432
    // aliases (lifetimes verified):
    __hip_bfloat16* kv_bf  = (__hip_bfloat16*)d_out;  // dead before final GEMM writes d_out
    __hip_bfloat16* cpl_bf = field_bf;                // wavecouple is in-place
    __hip_bfloat16* Ag     = x_bf;                    // x dead after the two x-GEMMs
    float* out = (float*)d_out;

    // converts
    f2bf_kernel<<<(M * DM / 4 + 255) / 256, 256, 0, stream>>>(x, x_bf, M * DM / 4);
    f2bf_kernel<<<(2 * DM * DM / 4 + 255) / 256, 256, 0, stream>>>(qkv_w + (size_t)DM * DM, wkv_bf, 2 * DM * DM / 4);
    f2bf_kernel<<<(DM * DM / 4 + 255) / 256, 256, 0, stream>>>(gate_w, wg_bf, DM * DM / 4);
    f2bf_kernel<<<(DM * DM / 4 + 255) / 256, 256, 0, stream>>>(out_w, wo_bf, DM * DM / 4);

    prep_kernel<<<1, 64, 0, stream>>>(scale_gain, field_coupling, gains, cwbuf);

    // kv = bf16(x @ W_kv^T + b_kv)  [16384, 2048] -> d_out scratch
    {
        dim3 grid(2 * DM / 128, M / 128);
        gemm128_kernel<<<grid, 256, 0, stream>>>(x_bf, wkv_bf, kv_bf, qkv_b + DM, M, 2 * DM, DM, 0, 1);
    }
    // gate = bf16(sigmoid(x @ gate_w^T + gate_b))  [16384, 1024]
    {
        dim3 grid(DM / 128, M / 128);
        gemm128_kernel<<<grid, 256, 0, stream>>>(x_bf, wg_bf, gate_bf, gate_b, M, DM, DM, 1, 1);
    }
    // field[b,c,n]
    {
        dim3 grid(SN / 64, NH, BD);
        fieldize_kernel<<<grid, 256, 0, stream>>>(kv_bf, field_bf);
    }
    // fused wavelet + coupling (in-place on field)
    wavecouple_kernel<<<BD * HD, 256, 0, stream>>>(gains, cwbuf, field_bf);
    // transpose + gate -> Ag bf16 [16384, 1024]
    {
        dim3 grid(SN / 64, DM / 64, BD);
        transgate_kernel<<<grid, 256, 0, stream>>>(cpl_bf, gate_bf, Ag);
    }
    // out = Ag @ out_w^T + out_b   (fp32 -> d_out)
    {
        dim3 grid(DM / 128, M / 128);
        gemm128_kernel<<<grid, 256, 0, stream>>>(Ag, wo_bf, out, out_b, M, DM, DM, 0, 0);
    }
}

// Round 4
// 417.264 us; speedup vs baseline: 1.8894x; 1.8894x over previous
//
#include <hip/hip_runtime.h>
#include <hip/hip_bf16.h>
#include <math.h>

// Problem constants
#define BD 8          // batch
#define SN 2048       // sequence length N
#define DM 1024       // d_model
#define NH 16         // heads
#define HD 64         // head dim
#define NS 11         // scales
#define NTAP 24       // unique wavelet offsets across 11 scales
#define PAD 3072      // max lookback = 3*2^10

typedef __attribute__((ext_vector_type(8))) short short8;
typedef __attribute__((ext_vector_type(4))) float floatx4;

// unique offsets (3-t)<<j, sorted
__constant__ int OFFS[NTAP] = {0, 1, 2, 3, 4, 6, 8, 12, 16, 24, 32, 48, 64, 96,
                               128, 192, 256, 384, 512, 768, 1024, 1536, 2048, 3072};

// async global->LDS, 16B per lane; LDS dest = wave-uniform base + lane*16
__device__ __forceinline__ void async_load16(const void* g, void* lds) {
    __builtin_amdgcn_global_load_lds(
        (const __attribute__((address_space(1))) void*)g,
        (__attribute__((address_space(3))) void*)lds,
        16, 0, 0);
}

// ---------------------------------------------------------------------------
// fp32 -> bf16 convert (vectorized by 4)
// ---------------------------------------------------------------------------
__global__ __launch_bounds__(256) void f2bf_kernel(const float* __restrict__ src,
                                                   __hip_bfloat16* __restrict__ dst,
                                                   int n4) {
    int i = blockIdx.x * 256 + threadIdx.x;
    if (i < n4) {
        const float4 v = reinterpret_cast<const float4*>(src)[i];
        union { __hip_bfloat16 h[4]; uint2 u; } cv;
        cv.h[0] = __float2bfloat16(v.x);
        cv.h[1] = __float2bfloat16(v.y);
        cv.h[2] = __float2bfloat16(v.z);
        cv.h[3] = __float2bfloat16(v.w);
        reinterpret_cast<uint2*>(dst)[i] = cv.u;
    }
}

// ---------------------------------------------------------------------------
// prep: softmaxes + per-head combined tap table
// wtab[i][h] = sum over (j,t) with (3-t)<<j == OFFS[i] of gains[j,h]*D4[t]
// ---------------------------------------------------------------------------
__global__ void prep_kernel(const float* __restrict__ scale_gain,
                            const float* __restrict__ field_coupling,
                            float* __restrict__ wtab,   // [NTAP][NH]
                            float* __restrict__ cw) {   // [NH][NH]
    const float D4[4] = {0.4829629131445341f, 0.8365163037378079f,
                         0.2241438680420134f, -0.1294095225512604f};
    int t = threadIdx.x;
    if (t < NH) {
        float g[NS];
        float m = -1e30f;
        for (int j = 0; j < NS; ++j) m = fmaxf(m, scale_gain[j * NH + t]);
        float s = 0.f;
        for (int j = 0; j < NS; ++j) { g[j] = expf(scale_gain[j * NH + t] - m); s += g[j]; }
        float inv = 1.f / s;
        for (int j = 0; j < NS; ++j) g[j] *= inv;
        for (int i = 0; i < NTAP; ++i) {
            float w = 0.f;
            for (int j = 0; j < NS; ++j)
                for (int tt = 0; tt < 4; ++tt)
                    if (((3 - tt) << j) == OFFS[i]) w += g[j] * D4[tt];
            wtab[i * NH + t] = w;
        }
    } else if (t < 2 * NH) {
        int r = t - NH;
        float m = -1e30f;
        for (int j = 0; j < NH; ++j) m = fmaxf(m, field_coupling[r * NH + j]);
        float e[NH]; float s = 0.f;
        for (int j = 0; j < NH; ++j) { e[j] = expf(field_coupling[r * NH + j] - m); s += e[j]; }
        float inv = 1.f / s;
        for (int j = 0; j < NH; ++j) cw[r * NH + j] = e[j] * inv;
    }
}

// ---------------------------------------------------------------------------
// m97-class bf16 MFMA GEMM: C[M,Nn] = A[M,K] @ Bw[Nn,K]^T + bias
// 128x128 tile, BK=64, 4 waves, 4x4 16x16x32 frags/wave; global_load_lds 16B
// with XOR-swizzled source chunks (LDS(row,chunk) = global chunk^(row&7)).
// ---------------------------------------------------------------------------
__global__ __launch_bounds__(256, 3) void gemm128_kernel(
    const __hip_bfloat16* __restrict__ A,
    const __hip_bfloat16* __restrict__ Bw,
    void* __restrict__ Cout,
    const float* __restrict__ bias,
    int M, int Nn, int K, int act, int bf16out) {
    __shared__ short As[128 * 64];   // 16 KB, row stride 128B, swizzled
    __shared__ short Bs[128 * 64];

    const int tid = threadIdx.x;
    const int m0 = blockIdx.y * 128;
    const int n0 = blockIdx.x * 128;
    const int wv = tid >> 6;
    const int ln = tid & 63;

    const int srow = ln >> 3;
    const int scc  = (ln & 7) ^ srow;
    size_t goffA[4], goffB[4];
    #pragma unroll
    for (int i = 0; i < 4; ++i) {
        const int row = wv * 32 + i * 8 + srow;
        goffA[i] = (size_t)(m0 + row) * K + scc * 8;
        goffB[i] = (size_t)(n0 + row) * K + scc * 8;
    }

    const int lrow = ln & 15, quad = ln >> 4;
    const int wm = (wv >> 1) * 64;
    const int wn = (wv & 1) * 64;
    int aaddr[4], baddr[4];
    #pragma unroll
    for (int t = 0; t < 4; ++t) {
        const int sw = (quad ^ (lrow & 7)) * 16;
        aaddr[t] = (wm + t * 16 + lrow) * 128 + sw;
        baddr[t] = (wn + t * 16 + lrow) * 128 + sw;
    }

    floatx4 acc[4][4];
    #pragma unroll
    for (int a = 0; a < 4; ++a)
        #pragma unroll
        for (int b = 0; b < 4; ++b) acc[a][b] = (floatx4){0.f, 0.f, 0.f, 0.f};

    for (int kt = 0; kt < K; kt += 64) {
        #pragma unroll
        for (int i = 0; i < 4; ++i) {
            async_load16(A + goffA[i] + kt, &As[(wv * 32 + i * 8) * 64]);
            async_load16(Bw + goffB[i] + kt, &Bs[(wv * 32 + i * 8) * 64]);
        }
        __syncthreads();
        #pragma unroll
        for (int h = 0; h < 2; ++h) {
            short8 a[4], b[4];
            #pragma unroll
            for (int t = 0; t < 4; ++t) {
                a[t] = *reinterpret_cast<const short8*>(
                           reinterpret_cast<const char*>(As) + (aaddr[t] ^ (h * 64)));
                b[t] = *reinterpret_cast<const short8*>(
                           reinterpret_cast<const char*>(Bs) + (baddr[t] ^ (h * 64)));
            }
            #pragma unroll
            for (int mt = 0; mt < 4; ++mt)
                #pragma unroll
                for (int nt = 0; nt < 4; ++nt)
                    acc[mt][nt] = __builtin_amdgcn_mfma_f32_16x16x32_bf16(
                        a[mt], b[nt], acc[mt][nt], 0, 0, 0);
        }
        __syncthreads();
    }

    #pragma unroll
    for (int mt = 0; mt < 4; ++mt) {
        #pragma unroll
        for (int nt = 0; nt < 4; ++nt) {
            const int col = n0 + wn + nt * 16 + lrow;
            const float bv = bias ? bias[col] : 0.f;
            #pragma unroll
            for (int i = 0; i < 4; ++i) {
                const int row = m0 + wm + mt * 16 + quad * 4 + i;
                float val = acc[mt][nt][i] + bv;
                if (act == 1) val = 1.f / (1.f + expf(-val));
                if (bf16out)
                    ((__hip_bfloat16*)Cout)[(size_t)row * Nn + col] = __float2bfloat16(val);
                else
                    ((float*)Cout)[(size_t)row * Nn + col] = val;
            }
        }
    }
}

// ---------------------------------------------------------------------------
// fieldize: field[b, h*64+d, n] = v[b,n,h,d] * ||k[b,n,h,:]||   (bf16 in/out)
// ---------------------------------------------------------------------------
__global__ __launch_bounds__(256) void fieldize_kernel(const __hip_bfloat16* __restrict__ kv,
                                                       __hip_bfloat16* __restrict__ field) {
    const int b = blockIdx.z, h = blockIdx.y, n0 = blockIdx.x * 64;
    __shared__ float kt[64][65];
    __shared__ float vt[64][65];
    __shared__ float mag[64];
    const int t = threadIdx.x;
    #pragma unroll
    for (int i = 0; i < 16; ++i) {
        int idx = t + i * 256;
        int nl = idx >> 6, d = idx & 63;
        size_t rbase = (size_t)(b * SN + n0 + nl) * 2048;
        kt[nl][d] = __bfloat162float(kv[rbase + h * 64 + d]);
        vt[nl][d] = __bfloat162float(kv[rbase + 1024 + h * 64 + d]);
    }
    __syncthreads();
    if (t < 64) {
        float s = 0.f;
        #pragma unroll
        for (int d = 0; d < 64; ++d) { float x = kt[t][d]; s += x * x; }
        mag[t] = sqrtf(s);
    }
    __syncthreads();
    #pragma unroll
    for (int i = 0; i < 16; ++i) {
        int idx = t + i * 256;
        int d = idx >> 6, nl = idx & 63;
        field[((size_t)b * DM + h * 64 + d) * SN + n0 + nl] =
            __float2bfloat16(vt[nl][d] * mag[nl]);
    }
}

// ---------------------------------------------------------------------------
// wavelet v2: per (b,c) row; zero-padded LDS row + 24-tap table.
// out[n] = sum_i wt[h][i] * row[n - OFFS[i]]  -- no branches, immediate offsets
// ---------------------------------------------------------------------------
__global__ __launch_bounds__(256) void wavelet_kernel(const __hip_bfloat16* __restrict__ field,
                                                      const float* __restrict__ wtab,
                                                      __hip_bfloat16* __restrict__ wave) {
    const int bc = blockIdx.x;          // b*1024 + c
    const int c = bc & (DM - 1);
    const int h = c >> 6;
    __shared__ float row[PAD + SN];     // 20 KB
    __shared__ float wt[NTAP];
    const __hip_bfloat16* src = field + (size_t)bc * SN;
    const int t = threadIdx.x;
    for (int i = t; i < PAD; i += 256) row[i] = 0.f;
    for (int i = t; i < SN; i += 256) row[PAD + i] = __bfloat162float(src[i]);
    if (t < NTAP) wt[t] = wtab[t * NH + h];
    __syncthreads();
    __hip_bfloat16* dst = wave + (size_t)bc * SN;
    for (int n = t; n < SN; n += 256) {
        const float* base = &row[PAD + n];
        float acc = 0.f;
        #pragma unroll
        for (int i = 0; i < NTAP; ++i) acc += wt[i] * base[-OFFS[i]];
        dst[n] = __float2bfloat16(acc);
    }
}

// ---------------------------------------------------------------------------
// head coupling: cpl[b, ho*64+d, n] = sum_hi cw[ho][hi] * wave[b, hi*64+d, n]
// ---------------------------------------------------------------------------
__global__ __launch_bounds__(256) void couple_kernel(const __hip_bfloat16* __restrict__ wave,
                                                     const float* __restrict__ cw,
                                                     __hip_bfloat16* __restrict__ cpl) {
    const int b = blockIdx.z, d = blockIdx.y;
    const int n = blockIdx.x * 256 + threadIdx.x;
    __shared__ float w[256];
    w[threadIdx.x] = cw[threadIdx.x];
    __syncthreads();
    size_t base = (size_t)b * DM * SN + (size_t)d * SN + n;
    float r[NH];
    #pragma unroll
    for (int hi = 0; hi < NH; ++hi) r[hi] = __bfloat162float(wave[base + (size_t)hi * 64 * SN]);
    #pragma unroll
    for (int ho = 0; ho < NH; ++ho) {
        float acc = 0.f;
        #pragma unroll
        for (int hi = 0; hi < NH; ++hi) acc += w[ho * 16 + hi] * r[hi];
        cpl[base + (size_t)ho * 64 * SN] = __float2bfloat16(acc);
    }
}

// ---------------------------------------------------------------------------
// transpose + gate: Ag[b*N+n, c] = bf16( cpl[b,c,n] * gate[b*N+n, c] )
// ---------------------------------------------------------------------------
__global__ __launch_bounds__(256) void transgate_kernel(const __hip_bfloat16* __restrict__ cpl,
                                                        const __hip_bfloat16* __restrict__ gate,
                                                        __hip_bfloat16* __restrict__ Ag) {
    const int b = blockIdx.z;
    const int c0 = blockIdx.y * 64, n0 = blockIdx.x * 64;
    __shared__ float tile[64][65];
    const int t = threadIdx.x;
    #pragma unroll
    for (int i = 0; i < 16; ++i) {
        int idx = t + i * 256;
        int ci = idx >> 6, nj = idx & 63;
        tile[ci][nj] = __bfloat162float(cpl[((size_t)b * DM + c0 + ci) * SN + n0 + nj]);
    }
    __syncthreads();
    #pragma unroll
    for (int i = 0; i < 16; ++i) {
        int idx = t + i * 256;
        int nj = idx >> 6, ci = idx & 63;
        size_t off = ((size_t)(b * SN + n0 + nj)) * DM + c0 + ci;
        Ag[off] = __float2bfloat16(tile[ci][nj] * __bfloat162float(gate[off]));
    }
}

// ---------------------------------------------------------------------------
// launch — ws footprint ~142.6 MB; kv staged in d_out (67,108,864 B)
// ---------------------------------------------------------------------------
extern "C" void kernel_launch(void* const* d_in, const int* in_sizes, int n_in,
                              void* d_out, int out_size, void* d_ws, size_t ws_size,
                              hipStream_t stream) {
    const float* x     = (const float*)d_in[0];
    const float* qkv_w = (const float*)d_in[1];
    const float* qkv_b = (const float*)d_in[2];
    const float* out_w = (const float*)d_in[3];
    const float* out_b = (const float*)d_in[4];
    const float* gate_w = (const float*)d_in[5];
    const float* gate_b = (const float*)d_in[6];
    const float* scale_gain = (const float*)d_in[7];
    const float* field_coupling = (const float*)d_in[8];

    char* ws = (char*)d_ws;
    const int M = BD * SN;          // 16384

    // ws layout (bytes)
    __hip_bfloat16* x_bf   = (__hip_bfloat16*)(ws);               // 33,554,432
    __hip_bfloat16* wkv_bf = (__hip_bfloat16*)(ws + 33554432);    //  4,194,304
    __hip_bfloat16* wg_bf  = (__hip_bfloat16*)(ws + 37748736);    //  2,097,152
    __hip_bfloat16* wo_bf  = (__hip_bfloat16*)(ws + 39845888);    //  2,097,152
    float* wtab            = (float*)(ws + 41943040);             //      1,536
    float* cwbuf           = (float*)(ws + 41944576);             //      1,024
    __hip_bfloat16* gate_bf  = (__hip_bfloat16*)(ws + 41945600);  // 33,554,432
    __hip_bfloat16* field_bf = (__hip_bfloat16*)(ws + 75500032);  // 33,554,432
    __hip_bfloat16* wave_bf  = (__hip_bfloat16*)(ws + 109054464); // 33,554,432
    // aliases (lifetimes verified):
    __hip_bfloat16* kv_bf  = (__hip_bfloat16*)d_out;  // dead before final GEMM writes d_out
    __hip_bfloat16* cpl_bf = field_bf;                // field dead after wavelet
    __hip_bfloat16* Ag     = x_bf;                    // x dead after the two x-GEMMs
    float* out = (float*)d_out;

    // converts
    f2bf_kernel<<<(M * DM / 4 + 255) / 256, 256, 0, stream>>>(x, x_bf, M * DM / 4);
    f2bf_kernel<<<(2 * DM * DM / 4 + 255) / 256, 256, 0, stream>>>(qkv_w + (size_t)DM * DM, wkv_bf, 2 * DM * DM / 4);
    f2bf_kernel<<<(DM * DM / 4 + 255) / 256, 256, 0, stream>>>(gate_w, wg_bf, DM * DM / 4);
    f2bf_kernel<<<(DM * DM / 4 + 255) / 256, 256, 0, stream>>>(out_w, wo_bf, DM * DM / 4);

    prep_kernel<<<1, 64, 0, stream>>>(scale_gain, field_coupling, wtab, cwbuf);

    // kv = bf16(x @ W_kv^T + b_kv)  [16384, 2048] -> d_out scratch
    {
        dim3 grid(2 * DM / 128, M / 128);
        gemm128_kernel<<<grid, 256, 0, stream>>>(x_bf, wkv_bf, kv_bf, qkv_b + DM, M, 2 * DM, DM, 0, 1);
    }
    // gate = bf16(sigmoid(x @ gate_w^T + gate_b))  [16384, 1024]
    {
        dim3 grid(DM / 128, M / 128);
        gemm128_kernel<<<grid, 256, 0, stream>>>(x_bf, wg_bf, gate_bf, gate_b, M, DM, DM, 1, 1);
    }
    // field[b,c,n]
    {
        dim3 grid(SN / 64, NH, BD);
        fieldize_kernel<<<grid, 256, 0, stream>>>(kv_bf, field_bf);
    }
    // wavelet (24-tap table)
    wavelet_kernel<<<BD * DM, 256, 0, stream>>>(field_bf, wtab, wave_bf);
    // coupling
    {
        dim3 grid(SN / 256, HD, BD);
        couple_kernel<<<grid, 256, 0, stream>>>(wave_bf, cwbuf, cpl_bf);
    }
    // transpose + gate -> Ag bf16 [16384, 1024]
    {
        dim3 grid(SN / 64, DM / 64, BD);
        transgate_kernel<<<grid, 256, 0, stream>>>(cpl_bf, gate_bf, Ag);
    }
    // out = Ag @ out_w^T + out_b   (fp32 -> d_out)
    {
        dim3 grid(DM / 128, M / 128);
        gemm128_kernel<<<grid, 256, 0, stream>>>(Ag, wo_bf, out, out_b, M, DM, DM, 0, 0);
    }
}

// Round 5
// 409.064 us; speedup vs baseline: 1.9273x; 1.0200x over previous
//
#include <hip/hip_runtime.h>
#include <hip/hip_bf16.h>
#include <math.h>

// Problem constants
#define BD 8          // batch
#define SN 2048       // sequence length N
#define DM 1024       // d_model
#define NH 16         // heads
#define HD 64         // head dim
#define NS 11         // scales
#define NTAP 24       // unique wavelet offsets across 11 scales
#define PAD 3072      // max lookback = 3*2^10

typedef __attribute__((ext_vector_type(8))) short short8;
typedef __attribute__((ext_vector_type(4))) float floatx4;

// unique offsets (3-t)<<j, sorted
__constant__ int OFFS[NTAP] = {0, 1, 2, 3, 4, 6, 8, 12, 16, 24, 32, 48, 64, 96,
                               128, 192, 256, 384, 512, 768, 1024, 1536, 2048, 3072};

// async global->LDS, 16B per lane; LDS dest = wave-uniform base + lane*16
__device__ __forceinline__ void async_load16(const void* g, void* lds) {
    __builtin_amdgcn_global_load_lds(
        (const __attribute__((address_space(1))) void*)g,
        (__attribute__((address_space(3))) void*)lds,
        16, 0, 0);
}

// ---------------------------------------------------------------------------
// fp32 -> bf16 convert (vectorized by 4)
// ---------------------------------------------------------------------------
__global__ __launch_bounds__(256) void f2bf_kernel(const float* __restrict__ src,
                                                   __hip_bfloat16* __restrict__ dst,
                                                   int n4) {
    int i = blockIdx.x * 256 + threadIdx.x;
    if (i < n4) {
        const float4 v = reinterpret_cast<const float4*>(src)[i];
        union { __hip_bfloat16 h[4]; uint2 u; } cv;
        cv.h[0] = __float2bfloat16(v.x);
        cv.h[1] = __float2bfloat16(v.y);
        cv.h[2] = __float2bfloat16(v.z);
        cv.h[3] = __float2bfloat16(v.w);
        reinterpret_cast<uint2*>(dst)[i] = cv.u;
    }
}

// ---------------------------------------------------------------------------
// prep: softmaxes + per-head tap table + kg bias concat
// ---------------------------------------------------------------------------
__global__ void prep_kernel(const float* __restrict__ scale_gain,
                            const float* __restrict__ field_coupling,
                            const float* __restrict__ qkv_b,
                            const float* __restrict__ gate_b,
                            float* __restrict__ wtab,    // [NTAP][NH]
                            float* __restrict__ cw,      // [NH][NH]
                            float* __restrict__ biascat) // [2048]: k bias | gate bias
{
    const float D4[4] = {0.4829629131445341f, 0.8365163037378079f,
                         0.2241438680420134f, -0.1294095225512604f};
    int t = threadIdx.x;
    if (t < NH) {
        float g[NS];
        float m = -1e30f;
        for (int j = 0; j < NS; ++j) m = fmaxf(m, scale_gain[j * NH + t]);
        float s = 0.f;
        for (int j = 0; j < NS; ++j) { g[j] = expf(scale_gain[j * NH + t] - m); s += g[j]; }
        float inv = 1.f / s;
        for (int j = 0; j < NS; ++j) g[j] *= inv;
        for (int i = 0; i < NTAP; ++i) {
            float w = 0.f;
            for (int j = 0; j < NS; ++j)
                for (int tt = 0; tt < 4; ++tt)
                    if (((3 - tt) << j) == OFFS[i]) w += g[j] * D4[tt];
            wtab[i * NH + t] = w;
        }
    } else if (t < 2 * NH) {
        int r = t - NH;
        float m = -1e30f;
        for (int j = 0; j < NH; ++j) m = fmaxf(m, field_coupling[r * NH + j]);
        float e[NH]; float s = 0.f;
        for (int j = 0; j < NH; ++j) { e[j] = expf(field_coupling[r * NH + j] - m); s += e[j]; }
        float inv = 1.f / s;
        for (int j = 0; j < NH; ++j) cw[r * NH + j] = e[j] * inv;
    }
    for (int i = t; i < 2048; i += 256)
        biascat[i] = (i < 1024) ? qkv_b[1024 + i] : gate_b[i - 1024];
}

// ---------------------------------------------------------------------------
// m97-class bf16 MFMA GEMM, 128x128 tile, BK=64, XOR-swizzled global_load_lds.
// mode 0: C fp32 = A@Bw^T + bias[col]                  (out GEMM)
// mode 1: C bf16 = A@Bw^T + bias[row]                  (v GEMM, swapped operands)
// mode 2: kg fused: cols<1024 -> kmag[h][r] = ||k+bias|| (no C write);
//         cols>=1024 -> gate bf16 = sigmoid(. + bias[col]), stored at col-1024
// ---------------------------------------------------------------------------
__global__ __launch_bounds__(256, 3) void gemm128_kernel(
    const __hip_bfloat16* __restrict__ A,
    const __hip_bfloat16* __restrict__ Bw,
    void* __restrict__ Cout,
    const float* __restrict__ bias,
    float* __restrict__ kmag,
    int M, int Nn, int K, int mode) {
    __shared__ short As[128 * 64];   // 16 KB, row stride 128B, swizzled
    __shared__ short Bs[128 * 64];

    const int tid = threadIdx.x;
    const int m0 = blockIdx.y * 128;
    const int n0 = blockIdx.x * 128;
    const int wv = tid >> 6;
    const int ln = tid & 63;

    const int srow = ln >> 3;
    const int scc  = (ln & 7) ^ srow;
    size_t goffA[4], goffB[4];
    #pragma unroll
    for (int i = 0; i < 4; ++i) {
        const int row = wv * 32 + i * 8 + srow;
        goffA[i] = (size_t)(m0 + row) * K + scc * 8;
        goffB[i] = (size_t)(n0 + row) * K + scc * 8;
    }

    const int lrow = ln & 15, quad = ln >> 4;
    const int wm = (wv >> 1) * 64;
    const int wn = (wv & 1) * 64;
    int aaddr[4], baddr[4];
    #pragma unroll
    for (int t = 0; t < 4; ++t) {
        const int sw = (quad ^ (lrow & 7)) * 16;
        aaddr[t] = (wm + t * 16 + lrow) * 128 + sw;
        baddr[t] = (wn + t * 16 + lrow) * 128 + sw;
    }

    floatx4 acc[4][4];
    #pragma unroll
    for (int a = 0; a < 4; ++a)
        #pragma unroll
        for (int b = 0; b < 4; ++b) acc[a][b] = (floatx4){0.f, 0.f, 0.f, 0.f};

    for (int kt = 0; kt < K; kt += 64) {
        #pragma unroll
        for (int i = 0; i < 4; ++i) {
            async_load16(A + goffA[i] + kt, &As[(wv * 32 + i * 8) * 64]);
            async_load16(Bw + goffB[i] + kt, &Bs[(wv * 32 + i * 8) * 64]);
        }
        __syncthreads();
        #pragma unroll
        for (int h = 0; h < 2; ++h) {
            short8 a[4], b[4];
            #pragma unroll
            for (int t = 0; t < 4; ++t) {
                a[t] = *reinterpret_cast<const short8*>(
                           reinterpret_cast<const char*>(As) + (aaddr[t] ^ (h * 64)));
                b[t] = *reinterpret_cast<const short8*>(
                           reinterpret_cast<const char*>(Bs) + (baddr[t] ^ (h * 64)));
            }
            #pragma unroll
            for (int mt = 0; mt < 4; ++mt)
                #pragma unroll
                for (int nt = 0; nt < 4; ++nt)
                    acc[mt][nt] = __builtin_amdgcn_mfma_f32_16x16x32_bf16(
                        a[mt], b[nt], acc[mt][nt], 0, 0, 0);
        }
        __syncthreads();
    }

    if (mode == 2 && n0 < 1024) {
        // k-norm epilogue: each wave's 64 cols = exactly one head
        const int h = (n0 + wn) >> 6;
        #pragma unroll
        for (int mt = 0; mt < 4; ++mt) {
            #pragma unroll
            for (int i = 0; i < 4; ++i) {
                float ss = 0.f;
                #pragma unroll
                for (int nt = 0; nt < 4; ++nt) {
                    const float v = acc[mt][nt][i] + bias[n0 + wn + nt * 16 + lrow];
                    ss += v * v;
                }
                ss += __shfl_xor(ss, 1);
                ss += __shfl_xor(ss, 2);
                ss += __shfl_xor(ss, 4);
                ss += __shfl_xor(ss, 8);
                if (lrow == 0) {
                    const int r = m0 + wm + mt * 16 + quad * 4 + i;
                    kmag[h * (BD * SN) + r] = sqrtf(ss);
                }
            }
        }
        return;
    }

    #pragma unroll
    for (int mt = 0; mt < 4; ++mt) {
        #pragma unroll
        for (int nt = 0; nt < 4; ++nt) {
            const int col = n0 + wn + nt * 16 + lrow;
            float bv = 0.f;
            if (bias && mode != 1) bv = bias[col];
            #pragma unroll
            for (int i = 0; i < 4; ++i) {
                const int row = m0 + wm + mt * 16 + quad * 4 + i;
                float val = acc[mt][nt][i] + bv;
                if (mode == 1 && bias) val += bias[row];
                if (mode == 0) {
                    ((float*)Cout)[(size_t)row * Nn + col] = val;
                } else if (mode == 1) {
                    ((__hip_bfloat16*)Cout)[(size_t)row * Nn + col] = __float2bfloat16(val);
                } else { // mode 2 gate region
                    val = 1.f / (1.f + expf(-val));
                    ((__hip_bfloat16*)Cout)[(size_t)row * 1024 + (col - 1024)] =
                        __float2bfloat16(val);
                }
            }
        }
    }
}

// ---------------------------------------------------------------------------
// wavelet: per (b,c) row; zero-padded LDS row + 24-tap table.
// input: fieldv[c][b*2048+n] (bf16, channel-major) scaled by kmag[h][b*2048+n]
// out[b*1024+c][n] = sum_i wt[h][i] * row[n - OFFS[i]]
// ---------------------------------------------------------------------------
__global__ __launch_bounds__(256) void wavelet_kernel(const __hip_bfloat16* __restrict__ fieldv,
                                                      const float* __restrict__ kmag,
                                                      const float* __restrict__ wtab,
                                                      __hip_bfloat16* __restrict__ wave) {
    const int bc = blockIdx.x;          // b*1024 + c
    const int b = bc >> 10;
    const int c = bc & (DM - 1);
    const int h = c >> 6;
    __shared__ float row[PAD + SN];     // 20 KB
    __shared__ float wt[NTAP];
    const __hip_bfloat16* src = fieldv + (size_t)c * (BD * SN) + b * SN;
    const float* mag = kmag + (size_t)h * (BD * SN) + b * SN;
    const int t = threadIdx.x;
    for (int i = t; i < PAD; i += 256) row[i] = 0.f;
    for (int i = t; i < SN; i += 256)
        row[PAD + i] = __bfloat162float(src[i]) * mag[i];
    if (t < NTAP) wt[t] = wtab[t * NH + h];
    __syncthreads();
    __hip_bfloat16* dst = wave + (size_t)bc * SN;
    for (int n = t; n < SN; n += 256) {
        const float* base = &row[PAD + n];
        float acc = 0.f;
        #pragma unroll
        for (int i = 0; i < NTAP; ++i) acc += wt[i] * base[-OFFS[i]];
        dst[n] = __float2bfloat16(acc);
    }
}

// ---------------------------------------------------------------------------
// head coupling: cpl[b, ho*64+d, n] = sum_hi cw[ho][hi] * wave[b, hi*64+d, n]
// ---------------------------------------------------------------------------
__global__ __launch_bounds__(256) void couple_kernel(const __hip_bfloat16* __restrict__ wave,
                                                     const float* __restrict__ cw,
                                                     __hip_bfloat16* __restrict__ cpl) {
    const int b = blockIdx.z, d = blockIdx.y;
    const int n = blockIdx.x * 256 + threadIdx.x;
    __shared__ float w[256];
    w[threadIdx.x] = cw[threadIdx.x];
    __syncthreads();
    size_t base = (size_t)b * DM * SN + (size_t)d * SN + n;
    float r[NH];
    #pragma unroll
    for (int hi = 0; hi < NH; ++hi) r[hi] = __bfloat162float(wave[base + (size_t)hi * 64 * SN]);
    #pragma unroll
    for (int ho = 0; ho < NH; ++ho) {
        float acc = 0.f;
        #pragma unroll
        for (int hi = 0; hi < NH; ++hi) acc += w[ho * 16 + hi] * r[hi];
        cpl[base + (size_t)ho * 64 * SN] = __float2bfloat16(acc);
    }
}

// ---------------------------------------------------------------------------
// transpose + gate: Ag[b*N+n, c] = bf16( cpl[b,c,n] * gate[b*N+n, c] )
// ---------------------------------------------------------------------------
__global__ __launch_bounds__(256) void transgate_kernel(const __hip_bfloat16* __restrict__ cpl,
                                                        const __hip_bfloat16* __restrict__ gate,
                                                        __hip_bfloat16* __restrict__ Ag) {
    const int b = blockIdx.z;
    const int c0 = blockIdx.y * 64, n0 = blockIdx.x * 64;
    __shared__ float tile[64][65];
    const int t = threadIdx.x;
    #pragma unroll
    for (int i = 0; i < 16; ++i) {
        int idx = t + i * 256;
        int ci = idx >> 6, nj = idx & 63;
        tile[ci][nj] = __bfloat162float(cpl[((size_t)b * DM + c0 + ci) * SN + n0 + nj]);
    }
    __syncthreads();
    #pragma unroll
    for (int i = 0; i < 16; ++i) {
        int idx = t + i * 256;
        int nj = idx >> 6, ci = idx & 63;
        size_t off = ((size_t)(b * SN + n0 + nj)) * DM + c0 + ci;
        Ag[off] = __float2bfloat16(tile[ci][nj] * __bfloat162float(gate[off]));
    }
}

// ---------------------------------------------------------------------------
// launch — ws footprint ~143.7 MB
// ---------------------------------------------------------------------------
extern "C" void kernel_launch(void* const* d_in, const int* in_sizes, int n_in,
                              void* d_out, int out_size, void* d_ws, size_t ws_size,
                              hipStream_t stream) {
    const float* x     = (const float*)d_in[0];
    const float* qkv_w = (const float*)d_in[1];
    const float* qkv_b = (const float*)d_in[2];
    const float* out_w = (const float*)d_in[3];
    const float* out_b = (const float*)d_in[4];
    const float* gate_w = (const float*)d_in[5];
    const float* gate_b = (const float*)d_in[6];
    const float* scale_gain = (const float*)d_in[7];
    const float* field_coupling = (const float*)d_in[8];

    char* ws = (char*)d_ws;
    const int M = BD * SN;          // 16384

    // ws layout (bytes)
    __hip_bfloat16* x_bf    = (__hip_bfloat16*)(ws);               // 33,554,432
    __hip_bfloat16* wkg_bf  = (__hip_bfloat16*)(ws + 33554432);    //  4,194,304  [2048,1024]: Wk | Wgate
    __hip_bfloat16* wv_bf   = (__hip_bfloat16*)(ws + 37748736);    //  2,097,152  [1024,1024]: Wv
    __hip_bfloat16* wo_bf   = (__hip_bfloat16*)(ws + 39845888);    //  2,097,152
    float* wtab             = (float*)(ws + 41943040);             //      1,536
    float* cwbuf            = (float*)(ws + 41944576);             //      1,024
    float* biascat          = (float*)(ws + 41945600);             //      8,192
    float* kmag             = (float*)(ws + 41953792);             //  1,048,576  [16][16384]
    __hip_bfloat16* fieldv  = (__hip_bfloat16*)(ws + 43002368);    // 33,554,432  [1024][16384]
    __hip_bfloat16* gate_bf = (__hip_bfloat16*)(ws + 76556800);    // 33,554,432
    __hip_bfloat16* wave_bf = (__hip_bfloat16*)(ws + 110111232);   // 33,554,432
    // aliases (lifetimes verified):
    __hip_bfloat16* cpl_bf = fieldv;   // fieldv dead after wavelet
    __hip_bfloat16* Ag     = x_bf;     // x dead after kg & v GEMMs
    float* out = (float*)d_out;

    // converts
    f2bf_kernel<<<(M * DM / 4 + 255) / 256, 256, 0, stream>>>(x, x_bf, M * DM / 4);
    f2bf_kernel<<<(DM * DM / 4 + 255) / 256, 256, 0, stream>>>(qkv_w + (size_t)DM * DM, wkg_bf, DM * DM / 4);
    f2bf_kernel<<<(DM * DM / 4 + 255) / 256, 256, 0, stream>>>(gate_w, wkg_bf + (size_t)DM * DM, DM * DM / 4);
    f2bf_kernel<<<(DM * DM / 4 + 255) / 256, 256, 0, stream>>>(qkv_w + (size_t)2 * DM * DM, wv_bf, DM * DM / 4);
    f2bf_kernel<<<(DM * DM / 4 + 255) / 256, 256, 0, stream>>>(out_w, wo_bf, DM * DM / 4);

    prep_kernel<<<1, 256, 0, stream>>>(scale_gain, field_coupling, qkv_b, gate_b,
                                       wtab, cwbuf, biascat);

    // kg GEMM: cols 0-1023 -> kmag only; cols 1024-2047 -> gate_bf (sigmoid)
    {
        dim3 grid(2 * DM / 128, M / 128);
        gemm128_kernel<<<grid, 256, 0, stream>>>(x_bf, wkg_bf, gate_bf, biascat, kmag,
                                                 M, 2 * DM, DM, 2);
    }
    // v GEMM (swapped): fieldv[c][r] = Wv @ x^T  (channel-major, no transpose needed)
    {
        dim3 grid(M / 128, DM / 128);
        gemm128_kernel<<<grid, 256, 0, stream>>>(wv_bf, x_bf, fieldv, qkv_b + 2 * DM, nullptr,
                                                 DM, M, DM, 1);
    }
    // wavelet (applies kmag inline)
    wavelet_kernel<<<BD * DM, 256, 0, stream>>>(fieldv, kmag, wtab, wave_bf);
    // coupling
    {
        dim3 grid(SN / 256, HD, BD);
        couple_kernel<<<grid, 256, 0, stream>>>(wave_bf, cwbuf, cpl_bf);
    }
    // transpose + gate -> Ag bf16 [16384, 1024]
    {
        dim3 grid(SN / 64, DM / 64, BD);
        transgate_kernel<<<grid, 256, 0, stream>>>(cpl_bf, gate_bf, Ag);
    }
    // out = Ag @ out_w^T + out_b   (fp32 -> d_out)
    {
        dim3 grid(DM / 128, M / 128);
        gemm128_kernel<<<grid, 256, 0, stream>>>(Ag, wo_bf, out, out_b, nullptr,
                                                 M, DM, DM, 0);
    }
}